// Round 9
// baseline (133.441 us; speedup 1.0000x reference)
//
#include <hip/hip_runtime.h>
#include <math.h>

namespace {
constexpr int Bn = 2, CF = 64;
constexpr int H = 256, W = 256, HW = H * W;
constexpr int IH = 512, IW = 512;

// ws layout in floats
constexpr int OFF_MT   = 0;                        // Mt[y][x], 256*256
constexpr int OFF_GXX  = OFF_MT + 256 * 256;       // [3][256] j-major
constexpr int OFF_GYY  = OFF_GXX + 3 * 256;        // [3][256]
constexpr int OFF_G    = OFF_GYY + 3 * 256;        // 3x3 = w_img^T w_img (pad 16)
constexpr int OFF_RIMG = OFF_G + 16;               // [b][c3][HW]
constexpr int OFF_S    = OFF_RIMG + Bn * 3 * HW;   // Bn*HW (stores SIGMOID(smap))
// PX/PY (32*256 each) overlay the RIMG region: consumed by gram_kernel
// before prep_kernel writes rimg (same stream => ordered).
constexpr int OFF_PX   = OFF_RIMG;
constexpr int OFF_PY   = OFF_RIMG + 32 * 256;
}

// ---------------------------------------------------------------------------
// P1: PX[o][t], PY[o][t] sinusoid projections. Transcendentals computed
// exactly 32x256 times total (per-block full recompute = R7's 43us trap).
// ---------------------------------------------------------------------------
__global__ __launch_bounds__(256) void pxy_kernel(
    const float* __restrict__ w_pos,
    float* __restrict__ PX, float* __restrict__ PY)
{
  const int t = threadIdx.x;
  const int o = blockIdx.x;
  float s[16], c[16];
#pragma unroll
  for (int i = 0; i < 16; i++) {
    float d = expf((float)(2 * i) * (-0.2878231366242557f)); // -ln(1e4)/32
    float a = (float)t * d;
    s[i] = sinf(a);
    c[i] = cosf(a);
  }
  const float* wr = w_pos + o * 64;
  float ax = 0.f, ay = 0.f;
#pragma unroll
  for (int i = 0; i < 16; i++) {
    ax += wr[2 * i] * s[i] + wr[2 * i + 1] * c[i];
    ay += wr[32 + 2 * i] * s[i] + wr[33 + 2 * i] * c[i];
  }
  PX[o * 256 + t] = ax;
  PY[o * 256 + t] = ay;
}

// ---------------------------------------------------------------------------
// P2: Mt[t][a] = dot_o(PX[:,a], PY[:,t]) (transposed so phigather reads
// coalesce). Block 0 also computes GXX/GYY (j-major) and G = w_img^T w_img.
// ---------------------------------------------------------------------------
__global__ __launch_bounds__(256) void gram_kernel(
    const float* __restrict__ PX, const float* __restrict__ PY,
    const float* __restrict__ w_img,
    float* __restrict__ Mt, float* __restrict__ GXX, float* __restrict__ GYY,
    float* __restrict__ G)
{
  const int a = threadIdx.x;
  const int t = blockIdx.x;

  float m = 0.f;
#pragma unroll
  for (int o = 0; o < 32; o++) m += PX[o * 256 + a] * PY[o * 256 + t];
  Mt[t * 256 + a] = m;

  if (t == 0) {
#pragma unroll
    for (int j = 0; j < 3; j++) {
      const int nb = a + 2 * (j - 1);
      float gx = 0.f, gy = 0.f;
      if (nb >= 0 && nb < 256) {
#pragma unroll
        for (int o = 0; o < 32; o++) {
          gx += PX[o * 256 + a] * PX[o * 256 + nb];
          gy += PY[o * 256 + a] * PY[o * 256 + nb];
        }
      }
      GXX[j * 256 + a] = gx;
      GYY[j * 256 + a] = gy;
    }
    if (a < 9) {
      const int i = a / 3, j = a % 3;
      float g = 0.f;
#pragma unroll
      for (int o = 0; o < 32; o++) g += w_img[o * 3 + i] * w_img[o * 3 + j];
      G[a] = g;
    }
  }
}

// ---------------------------------------------------------------------------
// prep_kernel (fused rimg + smap, block-routed):
//   blocks [0,768):   rimg[b][c][p] = antialiased 2x downsample of img
//   blocks [768,1792): smap[b][p] = SIGMOID(dot_c(inp[b,:,p], w_comp))
// ---------------------------------------------------------------------------
__device__ __forceinline__ void resize_taps(int p, int n, float w[4], int idx[4])
{
#pragma unroll
  for (int r = 0; r < 4; r++) {
    int q = 2 * p - 1 + r;
    idx[r] = min(max(q, 0), 2 * n - 1);
  }
  if (p == 0)          { w[0] = 0.f;        w[1] = 3.f / 7.f; w[2] = 3.f / 7.f; w[3] = 1.f / 7.f; }
  else if (p == n - 1) { w[0] = 1.f / 7.f;  w[1] = 3.f / 7.f; w[2] = 3.f / 7.f; w[3] = 0.f; }
  else                 { w[0] = 0.125f;     w[1] = 0.375f;    w[2] = 0.375f;    w[3] = 0.125f; }
}

__global__ __launch_bounds__(256) void prep_kernel(
    const float* __restrict__ img, const float* __restrict__ inp,
    const float* __restrict__ w_comp,
    float* __restrict__ rimg, float* __restrict__ smap)
{
  const int blk = blockIdx.x;
  const int b = blockIdx.z;

  if (blk < 768) {
    // ---- rimg part: c = blk>>8, 256 pixels per block ----
    const int c = blk >> 8;
    const int p = (blk & 255) * 256 + threadIdx.x;
    const int x = p & (W - 1);
    const int y = p >> 8;

    float wy[4], wx[4];
    int ry[4], rx[4];
    resize_taps(y, H, wy, ry);
    resize_taps(x, W, wx, rx);

    const float* ip = img + ((size_t)(b * 3 + c) * IH) * IW;
    float acc = 0.f;
#pragma unroll
    for (int r = 0; r < 4; r++) {
      const float* rowp = ip + ry[r] * IW;
      float rs = wx[0] * rowp[rx[0]] + wx[1] * rowp[rx[1]] +
                 wx[2] * rowp[rx[2]] + wx[3] * rowp[rx[3]];
      acc += wy[r] * rs;
    }
    rimg[((size_t)(b * 3 + c)) * HW + p] = acc;
  } else {
    // ---- smap part: 64 pixels x 4 ch-groups of 16, LDS reduce ----
    __shared__ float red[256];
    const int sb = blk - 768;                // 0..1023
    const int lane = threadIdx.x & 63;
    const int cg = threadIdx.x >> 6;         // 0..3
    const int p = sb * 64 + lane;

    const float* ib = inp + (size_t)b * CF * HW + (size_t)cg * 16 * HW + p;
    float a0 = 0.f, a1 = 0.f, a2 = 0.f, a3 = 0.f;
#pragma unroll
    for (int c = 0; c < 16; c += 4) {
      a0 += ib[(size_t)(c + 0) * HW] * w_comp[cg * 16 + c + 0];
      a1 += ib[(size_t)(c + 1) * HW] * w_comp[cg * 16 + c + 1];
      a2 += ib[(size_t)(c + 2) * HW] * w_comp[cg * 16 + c + 2];
      a3 += ib[(size_t)(c + 3) * HW] * w_comp[cg * 16 + c + 3];
    }
    red[threadIdx.x] = (a0 + a1) + (a2 + a3);
    __syncthreads();
    if (threadIdx.x < 64) {
      const float s = red[threadIdx.x] + red[threadIdx.x + 64] +
                      red[threadIdx.x + 128] + red[threadIdx.x + 192];
      smap[(size_t)b * HW + sb * 64 + threadIdx.x] = 1.f / (1.f + expf(-s));
    }
  }
}

// ---------------------------------------------------------------------------
// phigather (fused, pixel-PAIR float2): per thread (cg of 16 ch, pair, b):
//  phase 1: ph[k] (float2) = valid_k * sig(smap[nb_k]) *
//           ( rimg[p]^T G rimg[nb_k] + GXX[kx][x] + GYY[ky][y]
//             + Mt[y][cx] + Mt[cy][x] )
//  phase 2: out[c][p..p+1] += sum_k ph[k] * inp[c][nb_k..nb_k+1], 16 ch.
// All neighbor offsets are even and pairs are even-aligned, so validity is
// uniform per (k, pair); clamped bases stay in-bounds (even, <= W-2); any
// garbage at clamped edges is masked by valid=false (phi = 0).
// ---------------------------------------------------------------------------
__global__ __launch_bounds__(256) void phigather_kernel(
    const float* __restrict__ inp, const float* __restrict__ rimg,
    const float* __restrict__ smap, const float* __restrict__ Mt,
    const float* __restrict__ GXX, const float* __restrict__ GYY,
    const float* __restrict__ G, float* __restrict__ out)
{
  const int cg = blockIdx.x;               // 0..3, channels 16*cg..16*cg+15
  const int px = (blockIdx.y * 256 + threadIdx.x) * 2;  // even pixel
  const int b = blockIdx.z;
  const int x = px & (W - 1);              // even
  const int y = px >> 8;

  const float* rb = rimg + (size_t)b * 3 * HW;
  const float2 r0 = *(const float2*)(rb + px);
  const float2 r1 = *(const float2*)(rb + HW + px);
  const float2 r2 = *(const float2*)(rb + 2 * HW + px);
  const float g0 = G[0], g1 = G[1], g2 = G[2];
  const float g3 = G[3], g4 = G[4], g5 = G[5];
  const float g6 = G[6], g7 = G[7], g8 = G[8];
  const float* sb = smap + (size_t)b * HW;

  float2 ph[9];
  int nb[9];
#pragma unroll
  for (int k = 0; k < 9; k++) {
    const int ky = k / 3, kx = k % 3;
    const int ny = y + 2 * (ky - 1);
    const int nx = x + 2 * (kx - 1);       // even; pixel1 nx+1 valid iff nx valid
    const bool valid = ((unsigned)ny < (unsigned)H) & ((unsigned)nx < (unsigned)W);
    const int cy = min(max(ny, 0), H - 1);
    const int bx = min(max(nx, 0), W - 2); // even base, pair in-bounds
    const int np = cy * W + bx;
    nb[k] = np;

    const float2 n0 = *(const float2*)(rb + np);
    const float2 n1 = *(const float2*)(rb + HW + np);
    const float2 n2 = *(const float2*)(rb + 2 * HW + np);
    float2 fs;
    fs.x = r0.x * (g0 * n0.x + g1 * n1.x + g2 * n2.x)
         + r1.x * (g3 * n0.x + g4 * n1.x + g5 * n2.x)
         + r2.x * (g6 * n0.x + g7 * n1.x + g8 * n2.x);
    fs.y = r0.y * (g0 * n0.y + g1 * n1.y + g2 * n2.y)
         + r1.y * (g3 * n0.y + g4 * n1.y + g5 * n2.y)
         + r2.y * (g6 * n0.y + g7 * n1.y + g8 * n2.y);

    const float2 gxx = *(const float2*)(GXX + kx * 256 + x);
    const float gyy = GYY[ky * 256 + y];
    const float2 mA = *(const float2*)(Mt + y * 256 + bx);   // Mt[y][cx pair]
    const float2 mB = *(const float2*)(Mt + cy * 256 + x);   // Mt[cy][x,x+1]
    fs.x += gxx.x + gyy + mA.x + mB.x;
    fs.y += gxx.y + gyy + mA.y + mB.y;

    const float2 sg = *(const float2*)(sb + np);   // sigmoid precomputed
    ph[k].x = valid ? sg.x * fs.x : 0.f;
    ph[k].y = valid ? sg.y * fs.y : 0.f;
  }

  const float* ib = inp + (size_t)b * CF * HW + (size_t)cg * 16 * HW;
  float* ob = out + (size_t)b * CF * HW + (size_t)cg * 16 * HW;
#pragma unroll 4
  for (int c = 0; c < 16; c++) {
    const float* ic = ib + (size_t)c * HW;
    float2 v = *(const float2*)(ic + nb[0]);
    float ax = ph[0].x * v.x, ay = ph[0].y * v.y;
#pragma unroll
    for (int k = 1; k < 9; k++) {
      v = *(const float2*)(ic + nb[k]);
      ax += ph[k].x * v.x;
      ay += ph[k].y * v.y;
    }
    *(float2*)(ob + (size_t)c * HW + px) = make_float2(ax, ay);
  }
}

// ---------------------------------------------------------------------------
extern "C" void kernel_launch(void* const* d_in, const int* in_sizes, int n_in,
                              void* d_out, int out_size, void* d_ws, size_t ws_size,
                              hipStream_t stream)
{
  const float* inp    = (const float*)d_in[0];
  const float* img    = (const float*)d_in[1];
  const float* w_pos  = (const float*)d_in[2];
  const float* w_img  = (const float*)d_in[3];
  const float* w_comp = (const float*)d_in[4];
  float* out = (float*)d_out;
  float* ws  = (float*)d_ws;

  float* Mt   = ws + OFF_MT;
  float* GXX  = ws + OFF_GXX;
  float* GYY  = ws + OFF_GYY;
  float* G    = ws + OFF_G;
  float* rimg = ws + OFF_RIMG;
  float* smap = ws + OFF_S;
  float* PX   = ws + OFF_PX;   // overlays rimg (consumed before rimg written)
  float* PY   = ws + OFF_PY;

  hipLaunchKernelGGL(pxy_kernel, dim3(32), dim3(256), 0, stream, w_pos, PX, PY);
  hipLaunchKernelGGL(gram_kernel, dim3(256), dim3(256), 0, stream,
                     PX, PY, w_img, Mt, GXX, GYY, G);

  hipLaunchKernelGGL(prep_kernel, dim3(1792, 1, Bn), dim3(256), 0, stream,
                     img, inp, w_comp, rimg, smap);

  hipLaunchKernelGGL(phigather_kernel, dim3(CF / 16, HW / 512, Bn), dim3(256), 0, stream,
                     inp, rimg, smap, Mt, GXX, GYY, G, out);
}